// Round 8
// baseline (145.882 us; speedup 1.0000x reference)
//
#include <hip/hip_runtime.h>
#include <math.h>

// Problem constants
#define B_   8
#define L_   256
#define C_   512
#define OUT_ 512

typedef _Float16 half8 __attribute__((ext_vector_type(8)));
typedef _Float16 half4 __attribute__((ext_vector_type(4)));
typedef float    f32x4 __attribute__((ext_vector_type(4)));
typedef float    f32x2 __attribute__((ext_vector_type(2)));

// ---------------------------------------------------------------------------
// Kernel 0: Xh = (half)relu(X) for xt/xd, one pass. (R7-proven)
// ---------------------------------------------------------------------------
__global__ __launch_bounds__(256)
void prep_x_kernel(const float* __restrict__ xt, const float* __restrict__ xd,
                   _Float16* __restrict__ Xth, _Float16* __restrict__ Xdh)
{
    const int g = blockIdx.x * 256 + threadIdx.x;     // 0..262143 float4 index
    const float4 v1 = ((const float4*)xt)[g];
    half4 h1;
    h1[0] = (_Float16)fmaxf(v1.x, 0.f); h1[1] = (_Float16)fmaxf(v1.y, 0.f);
    h1[2] = (_Float16)fmaxf(v1.z, 0.f); h1[3] = (_Float16)fmaxf(v1.w, 0.f);
    ((half4*)Xth)[g] = h1;
    const float4 v2 = ((const float4*)xd)[g];
    half4 h2;
    h2[0] = (_Float16)fmaxf(v2.x, 0.f); h2[1] = (_Float16)fmaxf(v2.y, 0.f);
    h2[2] = (_Float16)fmaxf(v2.z, 0.f); h2[3] = (_Float16)fmaxf(v2.w, 0.f);
    ((half4*)Xdh)[g] = h2;
}

// ---------------------------------------------------------------------------
// Kernel 1: MFMA GEMM projections (R0 structure, R7 A-staging). Unchanged.
// ---------------------------------------------------------------------------
__global__ __launch_bounds__(256)
void proj_mfma_kernel(const _Float16* __restrict__ Xth, const float* __restrict__ Wp,
                      const float* __restrict__ bp,
                      const _Float16* __restrict__ Xdh, const float* __restrict__ Wc,
                      const float* __restrict__ bc,
                      _Float16* __restrict__ pt, _Float16* __restrict__ pc)
{
    const int which = blockIdx.z;
    const _Float16* __restrict__ X  = which ? Xdh : Xth;
    const float* __restrict__ W     = which ? Wc : Wp;
    const float* __restrict__ bias  = which ? bc : bp;
    _Float16*    __restrict__ Y     = which ? pc : pt;

    __shared__ _Float16 Ah[2][64][40];   // [buf][m][k]
    __shared__ _Float16 Bh[2][64][40];   // [buf][n][k]
    __shared__ _Float16 Ot[64][72];

    const int tid = threadIdx.x;
    const int m0 = blockIdx.y << 6, n0 = blockIdx.x << 6;
    const int lane = tid & 63, wv = tid >> 6;
    const int l15 = lane & 15, quad = lane >> 4;

    const int srow = tid >> 2, sch = (tid & 3) << 3;
    const _Float16* Ag = X + (size_t)(m0 + srow) * C_ + sch;
    const int nl = tid & 63, kseg = tid >> 6;
    const float* Bg = W + (size_t)(kseg << 3) * C_ + n0 + nl;

    half8 av = *(const half8*)Ag;
    float wr[8];
    #pragma unroll
    for (int r = 0; r < 8; ++r) wr[r] = Bg[(size_t)r * C_];

    {
        *(half8*)&Ah[0][srow][sch] = av;
        half8 bv;
        #pragma unroll
        for (int r = 0; r < 8; ++r) bv[r] = (_Float16)wr[r];
        *(half8*)&Bh[0][nl][kseg << 3] = bv;
    }

    f32x4 acc[4] = {};
    for (int ks = 0; ks < 16; ++ks) {
        const int cur = ks & 1;
        if (ks < 15) {
            Ag += 32;
            Bg += 32 * C_;
            av = *(const half8*)Ag;
            #pragma unroll
            for (int r = 0; r < 8; ++r) wr[r] = Bg[(size_t)r * C_];
        }
        __syncthreads();
        half8 af = *(const half8*)&Ah[cur][(wv << 4) + l15][quad << 3];
        #pragma unroll
        for (int nb = 0; nb < 4; ++nb) {
            half8 bf = *(const half8*)&Bh[cur][(nb << 4) + l15][quad << 3];
            acc[nb] = __builtin_amdgcn_mfma_f32_16x16x32_f16(af, bf, acc[nb], 0, 0, 0);
        }
        if (ks < 15) {
            *(half8*)&Ah[cur ^ 1][srow][sch] = av;
            half8 bv;
            #pragma unroll
            for (int r = 0; r < 8; ++r) bv[r] = (_Float16)wr[r];
            *(half8*)&Bh[cur ^ 1][nl][kseg << 3] = bv;
        }
    }

    __syncthreads();
    #pragma unroll
    for (int nb = 0; nb < 4; ++nb) {
        const float bz = bias[n0 + (nb << 4) + l15];
        #pragma unroll
        for (int r = 0; r < 4; ++r)
            Ot[(wv << 4) + (quad << 2) + r][(nb << 4) + l15] = (_Float16)(acc[nb][r] + bz);
    }
    __syncthreads();
    const int erow = tid >> 3, ech = (tid & 7) << 3;
    #pragma unroll
    for (int h = 0; h < 64; h += 32)
        *(half8*)&Y[(size_t)(m0 + erow + h) * C_ + n0 + ech] = *(const half8*)&Ot[erow + h][ech];
}

// ---------------------------------------------------------------------------
__device__ __forceinline__ float sigmoid_fast(float z) {
    float e = __builtin_amdgcn_exp2f(-1.4426950408889634f * z);
    return __builtin_amdgcn_rcpf(e + 1.0f);
}

// ---------------------------------------------------------------------------
// Kernel 2a (SPLIT OUT): sigmoid scores for one 16x32 tile per block.
// Score phase byte-identical to the R6/R7-proven fused body; sigmoid results
// now written to wglob (f32, layout [jh][j][i] = exactly the old ws LDS
// layout, flattened) + tile_sum. grid (128,8) x 512 thr.
// ---------------------------------------------------------------------------
__global__ __launch_bounds__(512)
void scores_kernel(const _Float16* __restrict__ pt, const _Float16* __restrict__ pc,
                   float* __restrict__ wglob, float* __restrict__ tile_sum)
{
    const int rm = blockIdx.x;            // tile 0..127
    const int b  = blockIdx.y;
    const int i0 = (rm >> 3) << 4;        // 16 i-rows
    const int j0 = (rm & 7) << 5;         // 32 j-rows
    const int tid = threadIdx.x;
    const int wv = tid >> 6, lane = tid & 63;
    const int l15 = lane & 15, quad = lane >> 4;

    __shared__ float red[8][256];         // 8 KB: split-k partial C tiles
    __shared__ float wred[8];

    // --- scores: wave wv -> (j-half = wv&1, k-quarter = wv>>1), K=128 each ---
    {
        const int jh = wv & 1, kq = wv >> 1;
        const _Float16* __restrict__ Ap =
            pt + (size_t)(b * L_ + i0 + l15) * C_ + (kq << 7) + (quad << 3);
        const _Float16* __restrict__ Bp =
            pc + (size_t)(b * L_ + j0 + (jh << 4) + l15) * C_ + (kq << 7) + (quad << 3);
        f32x4 acc = {};
        #pragma unroll
        for (int ks = 0; ks < 4; ++ks) {
            half8 af = *(const half8*)(Ap + (ks << 5));
            half8 bf = *(const half8*)(Bp + (ks << 5));
            acc = __builtin_amdgcn_mfma_f32_16x16x32_f16(af, bf, acc, 0, 0, 0);
        }
        *(f32x4*)&red[wv][lane << 2] = acc;
    }
    __syncthreads();
    {
        const int jh2 = tid >> 8, slot = tid & 255;
        const float sc = (red[jh2][slot]     + red[jh2 + 2][slot]) +
                         (red[jh2 + 4][slot] + red[jh2 + 6][slot]);
        const float z = sigmoid_fast(sc);
        const int ln = slot >> 2, r = slot & 3;
        // C/D layout: col(j) = ln&15, row(i) = (ln>>4)*4 + r ; store [jh][j][i]
        wglob[((size_t)((b << 7) | rm) << 9) + (jh2 << 8) +
              ((ln & 15) << 4) + ((ln >> 4) << 2) + r] = z;
        float lsum = z;
        #pragma unroll
        for (int off = 32; off; off >>= 1) lsum += __shfl_xor(lsum, off);
        if (lane == 0) wred[wv] = lsum;
    }
    __syncthreads();
    if (tid == 0) {
        float ts = 0.f;
        #pragma unroll
        for (int v = 0; v < 8; ++v) ts += wred[v];
        tile_sum[(b << 7) | rm] = ts;     // single writer, fixed order
    }
}

// ---------------------------------------------------------------------------
// Kernel 2b (v6): pure streaming weighted tanh-r. No MFMA, no LDS, no
// barriers. w read via WAVE-UNIFORM addresses from wglob -> compiler emits
// scalar loads (s_load, K$) feeding v_pk_fma SGPR operands: zero VALU/LDS
// issue cost for w (was 128 ds_read_b128/wave). Same math, same order as
// R6/R7 -> bit-identical output. grid (128,8) x 512 thr (thread = channel).
// ---------------------------------------------------------------------------
__global__ __launch_bounds__(512, 4)
void cp_tanh_kernel(const float* __restrict__ wglob,
                    const float* __restrict__ xd, const float* __restrict__ xt,
                    float* __restrict__ cpart)
{
    const int rm = blockIdx.x;            // tile 0..127
    const int b  = blockIdx.y;
    const int i0 = (rm >> 3) << 4;        // 16 i-rows
    const int j0 = (rm & 7) << 5;         // 32 j-rows
    const int tid = threadIdx.x;

    const float* __restrict__ xdb = xd + (size_t)(b * L_ + i0) * C_ + tid;
    const float* __restrict__ xtb = xt + (size_t)(b * L_ + j0) * C_ + tid;
    const float* __restrict__ wg  = wglob + ((size_t)((b << 7) | rm) << 9); // uniform

    f32x2 xds2[8];                        // 16 xd rows, prescaled by 2*log2(e)
    #pragma unroll
    for (int h = 0; h < 8; ++h) {
        xds2[h].x = xdb[(size_t)(2 * h) * C_]     * 2.8853900817779268f;
        xds2[h].y = xdb[(size_t)(2 * h + 1) * C_] * 2.8853900817779268f;
    }

    f32x2 acc01 = {0.f, 0.f}, acc23 = {0.f, 0.f};
    #pragma unroll 1
    for (int jh = 0; jh < 2; ++jh) {      // unroll 1: keeps xtv at 16 live regs
        float xtv[16];
        #pragma unroll
        for (int jj = 0; jj < 16; ++jj)
            xtv[jj] = xtb[(size_t)((jh << 4) + jj) * C_];
        const float* __restrict__ wrow0 = wg + (jh << 8);        // uniform
        #pragma unroll
        for (int jj = 0; jj < 16; ++jj) {
            const float xv = xtv[jj];
            const float* __restrict__ wrow = wrow0 + (jj << 4);  // uniform
            #pragma unroll
            for (int iq = 0; iq < 4; ++iq) {
                const float4 w4 = *(const float4*)(wrow + (iq << 2)); // s_load
                f32x2 x01 = xds2[iq * 2] * xv;                        // v_pk_mul
                f32x2 e01 = { __builtin_amdgcn_exp2f(x01.x), __builtin_amdgcn_exp2f(x01.y) };
                f32x2 q01 = e01 + 1.0f;
                float rp01 = __builtin_amdgcn_rcpf(q01.x * q01.y);
                f32x2 r01 = rp01 * __builtin_shufflevector(q01, q01, 1, 0);
                f32x2 w01 = { w4.x, w4.y };
                acc01 = w01 * r01 + acc01;                            // v_pk_fma
                f32x2 x23 = xds2[iq * 2 + 1] * xv;
                f32x2 e23 = { __builtin_amdgcn_exp2f(x23.x), __builtin_amdgcn_exp2f(x23.y) };
                f32x2 q23 = e23 + 1.0f;
                float rp23 = __builtin_amdgcn_rcpf(q23.x * q23.y);
                f32x2 r23 = rp23 * __builtin_shufflevector(q23, q23, 1, 0);
                f32x2 w23 = { w4.z, w4.w };
                acc23 = w23 * r23 + acc23;
            }
        }
    }
    cpart[(size_t)((b << 7) | rm) * C_ + tid] =      // single writer
        (acc01.x + acc01.y) + (acc23.x + acc23.y);
}

// ---------------------------------------------------------------------------
// Kernel 3: deterministic reduce + cp = 1-2s/S + out = cp@Wf + bf. (R6-proven)
// ---------------------------------------------------------------------------
__global__ __launch_bounds__(512)
void finalize_kernel(const float* __restrict__ cpart, const float* __restrict__ tile_sum,
                     const float* __restrict__ Wf, const float* __restrict__ bfv,
                     float* __restrict__ out)
{
    const int oc = blockIdx.x, b = blockIdx.y;
    const int tid = threadIdx.x;
    __shared__ float cp[C_];
    __shared__ float redf[512];

    // cp_raw[c] = sum over 128 tiles (fixed order)
    float s = 0.f;
    #pragma unroll 8
    for (int rm = 0; rm < 128; ++rm)
        s += cpart[(size_t)((b << 7) + rm) * C_ + tid];

    // S = sum of 128 tile sums (fixed tree)
    if (tid < 128) redf[tid] = tile_sum[(b << 7) + tid];
    __syncthreads();
    for (int st = 64; st > 0; st >>= 1) {
        if (tid < st) redf[tid] += redf[tid + st];
        __syncthreads();
    }
    const float S = redf[0];
    cp[tid] = 1.0f - 2.0f * s / S;
    __syncthreads();

    const int o = (oc << 5) | (tid & 31);         // 32 outputs per block
    const int c0 = (tid >> 5) << 5;               // 16 c-groups of 32
    float acc = 0.f;
    #pragma unroll 8
    for (int i = 0; i < 32; ++i) {
        const int cc = c0 + i;
        acc = fmaf(cp[cc], Wf[(size_t)cc * OUT_ + o], acc);
    }
    redf[tid] = acc;
    __syncthreads();
    if (tid < 32) {
        float a = 0.f;
        #pragma unroll
        for (int g = 0; g < 16; ++g) a += redf[(g << 5) | tid];
        out[(size_t)b * OUT_ + ((oc << 5) | tid)] = a + bfv[(oc << 5) | tid];
    }
}

// ---------------------------------------------------------------------------
extern "C" void kernel_launch(void* const* d_in, const int* in_sizes, int n_in,
                              void* d_out, int out_size, void* d_ws, size_t ws_size,
                              hipStream_t stream)
{
    (void)in_sizes; (void)n_in; (void)out_size; (void)ws_size;
    const float* xd = (const float*)d_in[0];
    const float* xt = (const float*)d_in[1];
    const float* Wc = (const float*)d_in[2];
    const float* bc = (const float*)d_in[3];
    const float* Wp = (const float*)d_in[4];
    const float* bp = (const float*)d_in[5];
    const float* Wf = (const float*)d_in[6];
    const float* bf = (const float*)d_in[7];
    float* out = (float*)d_out;

    // workspace (~12 MB), all single-writer -> no memset needed
    _Float16* Xth = (_Float16*)d_ws;                 // 2048x512 f16 = 2 MB
    _Float16* Xdh = Xth + 1048576;                   // 2 MB
    _Float16* pt  = Xdh + 1048576;                   // 2 MB
    _Float16* pc  = pt + 1048576;                    // 2 MB
    float* wglob    = (float*)(pc + 1048576);        // 1024x512 f32 = 2 MB
    float* cpart    = wglob + 524288;                // 1024x512 f32 = 2 MB
    float* tile_sum = cpart + 524288;                // 1024 f32

    prep_x_kernel<<<1024, 256, 0, stream>>>(xt, xd, Xth, Xdh);
    proj_mfma_kernel<<<dim3(8, 32, 2), 256, 0, stream>>>(Xth, Wp, bp, Xdh, Wc, bc, pt, pc);
    scores_kernel<<<dim3(128, 8), 512, 0, stream>>>(pt, pc, wglob, tile_sum);
    cp_tanh_kernel<<<dim3(128, 8), 512, 0, stream>>>(wglob, xd, xt, cpart);
    finalize_kernel<<<dim3(16, 8), 512, 0, stream>>>(cpart, tile_sum, Wf, bf, out);
}

// Round 12
// 141.529 us; speedup vs baseline: 1.0308x; 1.0308x over previous
//
#include <hip/hip_runtime.h>
#include <math.h>

// Problem constants
#define B_   8
#define L_   256
#define C_   512
#define OUT_ 512

typedef _Float16 half8 __attribute__((ext_vector_type(8)));
typedef _Float16 half4 __attribute__((ext_vector_type(4)));
typedef float    f32x4 __attribute__((ext_vector_type(4)));

// ---------------------------------------------------------------------------
// Kernel 0: Xh = (half)relu(X) for xt/xd, one pass. (R7-proven)
// ---------------------------------------------------------------------------
__global__ __launch_bounds__(256)
void prep_x_kernel(const float* __restrict__ xt, const float* __restrict__ xd,
                   _Float16* __restrict__ Xth, _Float16* __restrict__ Xdh)
{
    const int g = blockIdx.x * 256 + threadIdx.x;     // 0..262143 float4 index
    const float4 v1 = ((const float4*)xt)[g];
    half4 h1;
    h1[0] = (_Float16)fmaxf(v1.x, 0.f); h1[1] = (_Float16)fmaxf(v1.y, 0.f);
    h1[2] = (_Float16)fmaxf(v1.z, 0.f); h1[3] = (_Float16)fmaxf(v1.w, 0.f);
    ((half4*)Xth)[g] = h1;
    const float4 v2 = ((const float4*)xd)[g];
    half4 h2;
    h2[0] = (_Float16)fmaxf(v2.x, 0.f); h2[1] = (_Float16)fmaxf(v2.y, 0.f);
    h2[2] = (_Float16)fmaxf(v2.z, 0.f); h2[3] = (_Float16)fmaxf(v2.w, 0.f);
    ((half4*)Xdh)[g] = h2;
}

// ---------------------------------------------------------------------------
// Kernel 1: MFMA GEMM projections (R0 structure, R7 A-staging). Unchanged.
// ---------------------------------------------------------------------------
__global__ __launch_bounds__(256)
void proj_mfma_kernel(const _Float16* __restrict__ Xth, const float* __restrict__ Wp,
                      const float* __restrict__ bp,
                      const _Float16* __restrict__ Xdh, const float* __restrict__ Wc,
                      const float* __restrict__ bc,
                      _Float16* __restrict__ pt, _Float16* __restrict__ pc)
{
    const int which = blockIdx.z;
    const _Float16* __restrict__ X  = which ? Xdh : Xth;
    const float* __restrict__ W     = which ? Wc : Wp;
    const float* __restrict__ bias  = which ? bc : bp;
    _Float16*    __restrict__ Y     = which ? pc : pt;

    __shared__ _Float16 Ah[2][64][40];   // [buf][m][k]
    __shared__ _Float16 Bh[2][64][40];   // [buf][n][k]
    __shared__ _Float16 Ot[64][72];

    const int tid = threadIdx.x;
    const int m0 = blockIdx.y << 6, n0 = blockIdx.x << 6;
    const int lane = tid & 63, wv = tid >> 6;
    const int l15 = lane & 15, quad = lane >> 4;

    const int srow = tid >> 2, sch = (tid & 3) << 3;
    const _Float16* Ag = X + (size_t)(m0 + srow) * C_ + sch;
    const int nl = tid & 63, kseg = tid >> 6;
    const float* Bg = W + (size_t)(kseg << 3) * C_ + n0 + nl;

    half8 av = *(const half8*)Ag;
    float wr[8];
    #pragma unroll
    for (int r = 0; r < 8; ++r) wr[r] = Bg[(size_t)r * C_];

    {
        *(half8*)&Ah[0][srow][sch] = av;
        half8 bv;
        #pragma unroll
        for (int r = 0; r < 8; ++r) bv[r] = (_Float16)wr[r];
        *(half8*)&Bh[0][nl][kseg << 3] = bv;
    }

    f32x4 acc[4] = {};
    for (int ks = 0; ks < 16; ++ks) {
        const int cur = ks & 1;
        if (ks < 15) {
            Ag += 32;
            Bg += 32 * C_;
            av = *(const half8*)Ag;
            #pragma unroll
            for (int r = 0; r < 8; ++r) wr[r] = Bg[(size_t)r * C_];
        }
        __syncthreads();
        half8 af = *(const half8*)&Ah[cur][(wv << 4) + l15][quad << 3];
        #pragma unroll
        for (int nb = 0; nb < 4; ++nb) {
            half8 bf = *(const half8*)&Bh[cur][(nb << 4) + l15][quad << 3];
            acc[nb] = __builtin_amdgcn_mfma_f32_16x16x32_f16(af, bf, acc[nb], 0, 0, 0);
        }
        if (ks < 15) {
            *(half8*)&Ah[cur ^ 1][srow][sch] = av;
            half8 bv;
            #pragma unroll
            for (int r = 0; r < 8; ++r) bv[r] = (_Float16)wr[r];
            *(half8*)&Bh[cur ^ 1][nl][kseg << 3] = bv;
        }
    }

    __syncthreads();
    #pragma unroll
    for (int nb = 0; nb < 4; ++nb) {
        const float bz = bias[n0 + (nb << 4) + l15];
        #pragma unroll
        for (int r = 0; r < 4; ++r)
            Ot[(wv << 4) + (quad << 2) + r][(nb << 4) + l15] = (_Float16)(acc[nb][r] + bz);
    }
    __syncthreads();
    const int erow = tid >> 3, ech = (tid & 7) << 3;
    #pragma unroll
    for (int h = 0; h < 64; h += 32)
        *(half8*)&Y[(size_t)(m0 + erow + h) * C_ + n0 + ech] = *(const half8*)&Ot[erow + h][ech];
}

// ---------------------------------------------------------------------------
__device__ __forceinline__ float sigmoid_fast(float z) {
    float e = __builtin_amdgcn_exp2f(-1.4426950408889634f * z);
    return __builtin_amdgcn_rcpf(e + 1.0f);
}

// ---------------------------------------------------------------------------
// Kernel 2 (FUSED, v9): per 16x32 (i,j) tile: scores via 8-wave split-k MFMA
// + sigmoid -> ws LDS + tile_sum; then weighted tanh-r (thread = channel).
// v9 vs v4 (R6-proven): pure-scalar tanh loop with the pair-numerator
// reformulation  w_a*r_a + w_b*r_b = (w_a*q_b + w_b*q_a) * rcp(q_a*q_b)
// -- removes the two rp*q reconstruction muls and the vector shuffles
// (12 -> 11 instr/pair; no inline asm, no vector types in the hot loop).
// Overflow-safe: q<=~2e26; if q_a*q_b -> Inf, rcp -> 0 and n finite -> 0.
// grid (128, 8) x 512 thr. No atomics; single-writer outputs.
// ---------------------------------------------------------------------------
__global__ __launch_bounds__(512, 4)
void cp_tanh_kernel(const _Float16* __restrict__ pt, const _Float16* __restrict__ pc,
                    const float* __restrict__ xd, const float* __restrict__ xt,
                    float* __restrict__ cpart, float* __restrict__ tile_sum)
{
    const int rm = blockIdx.x;            // tile 0..127
    const int b  = blockIdx.y;
    const int i0 = (rm >> 3) << 4;        // 16 i-rows
    const int j0 = (rm & 7) << 5;         // 32 j-rows
    const int tid = threadIdx.x;
    const int wv = tid >> 6, lane = tid & 63;
    const int l15 = lane & 15, quad = lane >> 4;

    __shared__ float red[8][256];         // 8 KB: split-k partial C tiles
    __shared__ float ws[2][16][20];       // [j-half][j][i] sigmoid weights
    __shared__ float wred[8];

    // --- scores: wave wv -> (j-half = wv&1, k-quarter = wv>>1), K=128 each ---
    {
        const int jh = wv & 1, kq = wv >> 1;
        const _Float16* __restrict__ Ap =
            pt + (size_t)(b * L_ + i0 + l15) * C_ + (kq << 7) + (quad << 3);
        const _Float16* __restrict__ Bp =
            pc + (size_t)(b * L_ + j0 + (jh << 4) + l15) * C_ + (kq << 7) + (quad << 3);
        f32x4 acc = {};
        #pragma unroll
        for (int ks = 0; ks < 4; ++ks) {
            half8 af = *(const half8*)(Ap + (ks << 5));
            half8 bf = *(const half8*)(Bp + (ks << 5));
            acc = __builtin_amdgcn_mfma_f32_16x16x32_f16(af, bf, acc, 0, 0, 0);
        }
        *(f32x4*)&red[wv][lane << 2] = acc;
    }
    __syncthreads();
    {
        const int jh2 = tid >> 8, slot = tid & 255;
        const float sc = (red[jh2][slot]     + red[jh2 + 2][slot]) +
                         (red[jh2 + 4][slot] + red[jh2 + 6][slot]);
        const float z = sigmoid_fast(sc);
        const int ln = slot >> 2, r = slot & 3;
        // C/D layout: col(j) = ln&15, row(i) = (ln>>4)*4 + r ; store [j][i]
        ws[jh2][ln & 15][((ln >> 4) << 2) + r] = z;
        float lsum = z;
        #pragma unroll
        for (int off = 32; off; off >>= 1) lsum += __shfl_xor(lsum, off);
        if (lane == 0) wred[wv] = lsum;
    }
    __syncthreads();                      // ws + wred ready
    if (tid == 0) {
        float ts = 0.f;
        #pragma unroll
        for (int v = 0; v < 8; ++v) ts += wred[v];
        tile_sum[(b << 7) | rm] = ts;     // single writer, fixed order
    }

    // --- tanh-r: thread = channel; r = 1/(1+exp2(2*log2e*xd*xt)) ------------
    const float* __restrict__ xdb = xd + (size_t)(b * L_ + i0) * C_ + tid;
    const float* __restrict__ xtb = xt + (size_t)(b * L_ + j0) * C_ + tid;
    float xds[16];                        // 16 xd rows, prescaled by 2*log2(e)
    #pragma unroll
    for (int h = 0; h < 16; ++h)
        xds[h] = xdb[(size_t)h * C_] * 2.8853900817779268f;

    float acc0 = 0.f, acc1 = 0.f;
    #pragma unroll 1
    for (int jh = 0; jh < 2; ++jh) {      // unroll 1: keeps xtv at 16 live regs
        float xtv[16];
        #pragma unroll
        for (int jj = 0; jj < 16; ++jj)
            xtv[jj] = xtb[(size_t)((jh << 4) + jj) * C_];
        #pragma unroll
        for (int jj = 0; jj < 16; ++jj) {
            const float xv = xtv[jj];
            #pragma unroll
            for (int iq = 0; iq < 4; ++iq) {
                const float4 w4 = *(const float4*)&ws[jh][jj][iq << 2];  // bcast
                // pair (rows 4iq, 4iq+1)
                {
                    const float ea = __builtin_amdgcn_exp2f(xds[4 * iq]     * xv);
                    const float eb = __builtin_amdgcn_exp2f(xds[4 * iq + 1] * xv);
                    const float qa = ea + 1.0f, qb = eb + 1.0f;
                    const float nn = fmaf(w4.y, qa, w4.x * qb);
                    acc0 = fmaf(nn, __builtin_amdgcn_rcpf(qa * qb), acc0);
                }
                // pair (rows 4iq+2, 4iq+3)
                {
                    const float ec = __builtin_amdgcn_exp2f(xds[4 * iq + 2] * xv);
                    const float ed = __builtin_amdgcn_exp2f(xds[4 * iq + 3] * xv);
                    const float qc = ec + 1.0f, qd = ed + 1.0f;
                    const float nn = fmaf(w4.w, qc, w4.z * qd);
                    acc1 = fmaf(nn, __builtin_amdgcn_rcpf(qc * qd), acc1);
                }
            }
        }
    }
    cpart[(size_t)((b << 7) | rm) * C_ + tid] = acc0 + acc1;   // single writer
}

// ---------------------------------------------------------------------------
// Kernel 3: deterministic reduce + cp = 1-2s/S + out = cp@Wf + bf. (R6-proven)
// ---------------------------------------------------------------------------
__global__ __launch_bounds__(512)
void finalize_kernel(const float* __restrict__ cpart, const float* __restrict__ tile_sum,
                     const float* __restrict__ Wf, const float* __restrict__ bfv,
                     float* __restrict__ out)
{
    const int oc = blockIdx.x, b = blockIdx.y;
    const int tid = threadIdx.x;
    __shared__ float cp[C_];
    __shared__ float redf[512];

    // cp_raw[c] = sum over 128 tiles (fixed order)
    float s = 0.f;
    #pragma unroll 8
    for (int rm = 0; rm < 128; ++rm)
        s += cpart[(size_t)((b << 7) + rm) * C_ + tid];

    // S = sum of 128 tile sums (fixed tree)
    if (tid < 128) redf[tid] = tile_sum[(b << 7) + tid];
    __syncthreads();
    for (int st = 64; st > 0; st >>= 1) {
        if (tid < st) redf[tid] += redf[tid + st];
        __syncthreads();
    }
    const float S = redf[0];
    cp[tid] = 1.0f - 2.0f * s / S;
    __syncthreads();

    const int o = (oc << 5) | (tid & 31);         // 32 outputs per block
    const int c0 = (tid >> 5) << 5;               // 16 c-groups of 32
    float acc = 0.f;
    #pragma unroll 8
    for (int i = 0; i < 32; ++i) {
        const int cc = c0 + i;
        acc = fmaf(cp[cc], Wf[(size_t)cc * OUT_ + o], acc);
    }
    redf[tid] = acc;
    __syncthreads();
    if (tid < 32) {
        float a = 0.f;
        #pragma unroll
        for (int g = 0; g < 16; ++g) a += redf[(g << 5) | tid];
        out[(size_t)b * OUT_ + ((oc << 5) | tid)] = a + bfv[(oc << 5) | tid];
    }
}

// ---------------------------------------------------------------------------
extern "C" void kernel_launch(void* const* d_in, const int* in_sizes, int n_in,
                              void* d_out, int out_size, void* d_ws, size_t ws_size,
                              hipStream_t stream)
{
    (void)in_sizes; (void)n_in; (void)out_size; (void)ws_size;
    const float* xd = (const float*)d_in[0];
    const float* xt = (const float*)d_in[1];
    const float* Wc = (const float*)d_in[2];
    const float* bc = (const float*)d_in[3];
    const float* Wp = (const float*)d_in[4];
    const float* bp = (const float*)d_in[5];
    const float* Wf = (const float*)d_in[6];
    const float* bf = (const float*)d_in[7];
    float* out = (float*)d_out;

    // workspace (~10 MB), all single-writer -> no memset needed
    _Float16* Xth = (_Float16*)d_ws;                 // 2048x512 f16 = 2 MB
    _Float16* Xdh = Xth + 1048576;                   // 2 MB
    _Float16* pt  = Xdh + 1048576;                   // 2 MB
    _Float16* pc  = pt + 1048576;                    // 2 MB
    float* cpart    = (float*)(pc + 1048576);        // 1024x512 f32 = 2 MB
    float* tile_sum = cpart + 524288;                // 1024 f32

    prep_x_kernel<<<1024, 256, 0, stream>>>(xt, xd, Xth, Xdh);
    proj_mfma_kernel<<<dim3(8, 32, 2), 256, 0, stream>>>(Xth, Wp, bp, Xdh, Wc, bc, pt, pc);
    cp_tanh_kernel<<<dim3(128, 8), 512, 0, stream>>>(pt, pc, xd, xt, cpart, tile_sum);
    finalize_kernel<<<dim3(16, 8), 512, 0, stream>>>(cpart, tile_sum, Wf, bf, out);
}

// Round 13
// 137.654 us; speedup vs baseline: 1.0598x; 1.0281x over previous
//
#include <hip/hip_runtime.h>
#include <math.h>

// Problem constants
#define B_   8
#define L_   256
#define C_   512
#define OUT_ 512

typedef _Float16 half8 __attribute__((ext_vector_type(8)));
typedef _Float16 half4 __attribute__((ext_vector_type(4)));
typedef float    f32x4 __attribute__((ext_vector_type(4)));
typedef float    f32x2 __attribute__((ext_vector_type(2)));

// ---------------------------------------------------------------------------
// FINAL (revert to R6 = best measured, 137.27us): session post-mortem showed
// every cp_tanh variant after R6 was neutral or worse (split: +5us, hoist: 0,
// pk-asm: broken, pair-numerator: +5us via VGPR 48 + longer dep chain). The
// R6 tanh loop's 42cy/pair issue = exact scalar instruction count -> at the
// serialized VALU+trans floor for this factorization.
// ---------------------------------------------------------------------------

// ---------------------------------------------------------------------------
// Kernel 1: MFMA relu-GEMM projections (R0-proven version, verbatim).
//   Y[m][n] = sum_k relu(X[m][k]) * W[k][n] + bias[n],  W raw f32 [k][n].
// 64x64 tile, KT=32, LDS double-buffer, 1 barrier/step. grid (8,32,2), 256thr.
// ---------------------------------------------------------------------------
__global__ __launch_bounds__(256)
void proj_mfma_kernel(const float* __restrict__ xt, const float* __restrict__ Wp,
                      const float* __restrict__ bp,
                      const float* __restrict__ xd, const float* __restrict__ Wc,
                      const float* __restrict__ bc,
                      _Float16* __restrict__ pt, _Float16* __restrict__ pc)
{
    const int which = blockIdx.z;
    const float* __restrict__ X    = which ? xd : xt;
    const float* __restrict__ W    = which ? Wc : Wp;
    const float* __restrict__ bias = which ? bc : bp;
    _Float16*    __restrict__ Y    = which ? pc : pt;

    __shared__ _Float16 Ah[2][64][40];   // [buf][m][k]
    __shared__ _Float16 Bh[2][64][40];   // [buf][n][k]
    __shared__ _Float16 Ot[64][72];

    const int tid = threadIdx.x;
    const int m0 = blockIdx.y << 6, n0 = blockIdx.x << 6;
    const int lane = tid & 63, wv = tid >> 6;
    const int l15 = lane & 15, quad = lane >> 4;

    const int srow = tid >> 2, sch = (tid & 3) << 3;
    const float* Ag = X + (size_t)(m0 + srow) * C_ + sch;
    const int nl = tid & 63, kseg = tid >> 6;
    const float* Bg = W + (size_t)(kseg << 3) * C_ + n0 + nl;

    float4 a0 = *(const float4*)(Ag);
    float4 a1 = *(const float4*)(Ag + 4);
    float wr[8];
    #pragma unroll
    for (int r = 0; r < 8; ++r) wr[r] = Bg[(size_t)r * C_];

    {
        half8 av;
        av[0] = (_Float16)fmaxf(a0.x, 0.f); av[1] = (_Float16)fmaxf(a0.y, 0.f);
        av[2] = (_Float16)fmaxf(a0.z, 0.f); av[3] = (_Float16)fmaxf(a0.w, 0.f);
        av[4] = (_Float16)fmaxf(a1.x, 0.f); av[5] = (_Float16)fmaxf(a1.y, 0.f);
        av[6] = (_Float16)fmaxf(a1.z, 0.f); av[7] = (_Float16)fmaxf(a1.w, 0.f);
        *(half8*)&Ah[0][srow][sch] = av;
        half8 bv;
        #pragma unroll
        for (int r = 0; r < 8; ++r) bv[r] = (_Float16)wr[r];
        *(half8*)&Bh[0][nl][kseg << 3] = bv;
    }

    f32x4 acc[4] = {};
    for (int ks = 0; ks < 16; ++ks) {
        const int cur = ks & 1;
        if (ks < 15) {
            Ag += 32;
            Bg += 32 * C_;
            a0 = *(const float4*)(Ag);
            a1 = *(const float4*)(Ag + 4);
            #pragma unroll
            for (int r = 0; r < 8; ++r) wr[r] = Bg[(size_t)r * C_];
        }
        __syncthreads();
        half8 af = *(const half8*)&Ah[cur][(wv << 4) + l15][quad << 3];
        #pragma unroll
        for (int nb = 0; nb < 4; ++nb) {
            half8 bf = *(const half8*)&Bh[cur][(nb << 4) + l15][quad << 3];
            acc[nb] = __builtin_amdgcn_mfma_f32_16x16x32_f16(af, bf, acc[nb], 0, 0, 0);
        }
        if (ks < 15) {
            half8 av;
            av[0] = (_Float16)fmaxf(a0.x, 0.f); av[1] = (_Float16)fmaxf(a0.y, 0.f);
            av[2] = (_Float16)fmaxf(a0.z, 0.f); av[3] = (_Float16)fmaxf(a0.w, 0.f);
            av[4] = (_Float16)fmaxf(a1.x, 0.f); av[5] = (_Float16)fmaxf(a1.y, 0.f);
            av[6] = (_Float16)fmaxf(a1.z, 0.f); av[7] = (_Float16)fmaxf(a1.w, 0.f);
            *(half8*)&Ah[cur ^ 1][srow][sch] = av;
            half8 bv;
            #pragma unroll
            for (int r = 0; r < 8; ++r) bv[r] = (_Float16)wr[r];
            *(half8*)&Bh[cur ^ 1][nl][kseg << 3] = bv;
        }
    }

    __syncthreads();
    #pragma unroll
    for (int nb = 0; nb < 4; ++nb) {
        const float bz = bias[n0 + (nb << 4) + l15];
        #pragma unroll
        for (int r = 0; r < 4; ++r)
            Ot[(wv << 4) + (quad << 2) + r][(nb << 4) + l15] = (_Float16)(acc[nb][r] + bz);
    }
    __syncthreads();
    const int erow = tid >> 3, ech = (tid & 7) << 3;
    #pragma unroll
    for (int h = 0; h < 64; h += 32)
        *(half8*)&Y[(size_t)(m0 + erow + h) * C_ + n0 + ech] = *(const half8*)&Ot[erow + h][ech];
}

// ---------------------------------------------------------------------------
__device__ __forceinline__ float sigmoid_fast(float z) {
    float e = __builtin_amdgcn_exp2f(-1.4426950408889634f * z);
    return __builtin_amdgcn_rcpf(e + 1.0f);
}

// ---------------------------------------------------------------------------
// Kernel 2 (FUSED, v4 = R6-proven): per 16x32 (i,j) tile: scores via 8-wave
// split-k MFMA + sigmoid -> ws LDS + tile_sum; then weighted tanh-r
// (thread = channel). LB(512,4): body fits 36 VGPR, 4 blocks/CU.
// Loads after the score phase (short live ranges; TLP hides latency).
// grid (128, 8) x 512 thr. No atomics; single-writer outputs.
// ---------------------------------------------------------------------------
__global__ __launch_bounds__(512, 4)
void cp_tanh_kernel(const _Float16* __restrict__ pt, const _Float16* __restrict__ pc,
                    const float* __restrict__ xd, const float* __restrict__ xt,
                    float* __restrict__ cpart, float* __restrict__ tile_sum)
{
    const int rm = blockIdx.x;            // tile 0..127
    const int b  = blockIdx.y;
    const int i0 = (rm >> 3) << 4;        // 16 i-rows
    const int j0 = (rm & 7) << 5;         // 32 j-rows
    const int tid = threadIdx.x;
    const int wv = tid >> 6, lane = tid & 63;
    const int l15 = lane & 15, quad = lane >> 4;

    __shared__ float red[8][256];         // 8 KB: split-k partial C tiles
    __shared__ float ws[2][16][20];       // [j-half][j][i] sigmoid weights
    __shared__ float wred[8];

    // --- scores: wave wv -> (j-half = wv&1, k-quarter = wv>>1), K=128 each ---
    {
        const int jh = wv & 1, kq = wv >> 1;
        const _Float16* __restrict__ Ap =
            pt + (size_t)(b * L_ + i0 + l15) * C_ + (kq << 7) + (quad << 3);
        const _Float16* __restrict__ Bp =
            pc + (size_t)(b * L_ + j0 + (jh << 4) + l15) * C_ + (kq << 7) + (quad << 3);
        f32x4 acc = {};
        #pragma unroll
        for (int ks = 0; ks < 4; ++ks) {
            half8 af = *(const half8*)(Ap + (ks << 5));
            half8 bf = *(const half8*)(Bp + (ks << 5));
            acc = __builtin_amdgcn_mfma_f32_16x16x32_f16(af, bf, acc, 0, 0, 0);
        }
        *(f32x4*)&red[wv][lane << 2] = acc;
    }
    __syncthreads();
    {
        const int jh2 = tid >> 8, slot = tid & 255;
        const float sc = (red[jh2][slot]     + red[jh2 + 2][slot]) +
                         (red[jh2 + 4][slot] + red[jh2 + 6][slot]);
        const float z = sigmoid_fast(sc);
        const int ln = slot >> 2, r = slot & 3;
        // C/D layout: col(j) = ln&15, row(i) = (ln>>4)*4 + r ; store [j][i]
        ws[jh2][ln & 15][((ln >> 4) << 2) + r] = z;
        float lsum = z;
        #pragma unroll
        for (int off = 32; off; off >>= 1) lsum += __shfl_xor(lsum, off);
        if (lane == 0) wred[wv] = lsum;
    }
    __syncthreads();                      // ws + wred ready
    if (tid == 0) {
        float ts = 0.f;
        #pragma unroll
        for (int v = 0; v < 8; ++v) ts += wred[v];
        tile_sum[(b << 7) | rm] = ts;     // single writer, fixed order
    }

    // --- tanh-r: thread = channel; r = 1/(1+exp2(2*log2e*xd*xt)) ------------
    // loads AFTER the score phase (short live ranges; TLP hides latency)
    const float* __restrict__ xdb = xd + (size_t)(b * L_ + i0) * C_ + tid;
    const float* __restrict__ xtb = xt + (size_t)(b * L_ + j0) * C_ + tid;
    f32x2 xds2[8];                        // 16 xd rows, prescaled by 2*log2(e)
    #pragma unroll
    for (int h = 0; h < 8; ++h) {
        xds2[h].x = xdb[(size_t)(2 * h) * C_]     * 2.8853900817779268f;
        xds2[h].y = xdb[(size_t)(2 * h + 1) * C_] * 2.8853900817779268f;
    }

    f32x2 acc01 = {0.f, 0.f}, acc23 = {0.f, 0.f};
    #pragma unroll 1
    for (int jh = 0; jh < 2; ++jh) {      // unroll 1: keeps xtv at 16 live regs
        float xtv[16];
        #pragma unroll
        for (int jj = 0; jj < 16; ++jj)
            xtv[jj] = xtb[(size_t)((jh << 4) + jj) * C_];
        #pragma unroll
        for (int jj = 0; jj < 16; ++jj) {
            const float xv = xtv[jj];
            #pragma unroll
            for (int iq = 0; iq < 4; ++iq) {
                const float4 w4 = *(const float4*)&ws[jh][jj][iq << 2];  // bcast
                f32x2 x01 = xds2[iq * 2] * xv;
                f32x2 e01 = { __builtin_amdgcn_exp2f(x01.x), __builtin_amdgcn_exp2f(x01.y) };
                f32x2 q01 = e01 + 1.0f;
                float rp01 = __builtin_amdgcn_rcpf(q01.x * q01.y);
                f32x2 r01 = rp01 * __builtin_shufflevector(q01, q01, 1, 0);
                f32x2 w01 = { w4.x, w4.y };
                acc01 = w01 * r01 + acc01;
                f32x2 x23 = xds2[iq * 2 + 1] * xv;
                f32x2 e23 = { __builtin_amdgcn_exp2f(x23.x), __builtin_amdgcn_exp2f(x23.y) };
                f32x2 q23 = e23 + 1.0f;
                float rp23 = __builtin_amdgcn_rcpf(q23.x * q23.y);
                f32x2 r23 = rp23 * __builtin_shufflevector(q23, q23, 1, 0);
                f32x2 w23 = { w4.z, w4.w };
                acc23 = w23 * r23 + acc23;
            }
        }
    }
    cpart[(size_t)((b << 7) | rm) * C_ + tid] =      // single writer
        (acc01.x + acc01.y) + (acc23.x + acc23.y);
}

// ---------------------------------------------------------------------------
// Kernel 3: deterministic reduce + cp = 1-2s/S + out = cp@Wf + bf.
// grid (16,8) [x = 32-out chunk, y = b], 512 thr. (R6-proven.)
// ---------------------------------------------------------------------------
__global__ __launch_bounds__(512)
void finalize_kernel(const float* __restrict__ cpart, const float* __restrict__ tile_sum,
                     const float* __restrict__ Wf, const float* __restrict__ bfv,
                     float* __restrict__ out)
{
    const int oc = blockIdx.x, b = blockIdx.y;
    const int tid = threadIdx.x;
    __shared__ float cp[C_];
    __shared__ float redf[512];

    // cp_raw[c] = sum over 128 tiles (fixed order)
    float s = 0.f;
    #pragma unroll 8
    for (int rm = 0; rm < 128; ++rm)
        s += cpart[(size_t)((b << 7) + rm) * C_ + tid];

    // S = sum of 128 tile sums (fixed tree)
    if (tid < 128) redf[tid] = tile_sum[(b << 7) + tid];
    __syncthreads();
    for (int st = 64; st > 0; st >>= 1) {
        if (tid < st) redf[tid] += redf[tid + st];
        __syncthreads();
    }
    const float S = redf[0];
    cp[tid] = 1.0f - 2.0f * s / S;
    __syncthreads();

    const int o = (oc << 5) | (tid & 31);         // 32 outputs per block
    const int c0 = (tid >> 5) << 5;               // 16 c-groups of 32
    float acc = 0.f;
    #pragma unroll 8
    for (int i = 0; i < 32; ++i) {
        const int cc = c0 + i;
        acc = fmaf(cp[cc], Wf[(size_t)cc * OUT_ + o], acc);
    }
    redf[tid] = acc;
    __syncthreads();
    if (tid < 32) {
        float a = 0.f;
        #pragma unroll
        for (int g = 0; g < 16; ++g) a += redf[(g << 5) | tid];
        out[(size_t)b * OUT_ + ((oc << 5) | tid)] = a + bfv[(oc << 5) | tid];
    }
}

// ---------------------------------------------------------------------------
extern "C" void kernel_launch(void* const* d_in, const int* in_sizes, int n_in,
                              void* d_out, int out_size, void* d_ws, size_t ws_size,
                              hipStream_t stream)
{
    (void)in_sizes; (void)n_in; (void)out_size; (void)ws_size;
    const float* xd = (const float*)d_in[0];
    const float* xt = (const float*)d_in[1];
    const float* Wc = (const float*)d_in[2];
    const float* bc = (const float*)d_in[3];
    const float* Wp = (const float*)d_in[4];
    const float* bp = (const float*)d_in[5];
    const float* Wf = (const float*)d_in[6];
    const float* bf = (const float*)d_in[7];
    float* out = (float*)d_out;

    // workspace (~6 MB), all single-writer -> no memset needed
    _Float16* pt = (_Float16*)d_ws;                  // 2048x512 f16 = 2 MB
    _Float16* pc = pt + 1048576;                     // 2 MB
    float* cpart    = (float*)(pc + 1048576);        // 1024x512 f32 = 2 MB
    float* tile_sum = cpart + 524288;                // 1024 f32

    proj_mfma_kernel<<<dim3(8, 32, 2), 256, 0, stream>>>(xt, Wp, bp, xd, Wc, bc, pt, pc);
    cp_tanh_kernel<<<dim3(128, 8), 512, 0, stream>>>(pt, pc, xd, xt, cpart, tile_sum);
    finalize_kernel<<<dim3(16, 8), 512, 0, stream>>>(cpart, tile_sum, Wf, bf, out);
}